// Round 2
// baseline (6020.772 us; speedup 1.0000x reference)
//
#include <hip/hip_runtime.h>

#define EPSV 1e-4f
#define REG 484   // floats per matrix LDS region (15x32 staging / Vl / Ut / Wl+hl+tri)

typedef float v2f __attribute__((ext_vector_type(2)));

__device__ __forceinline__ float bperm(int addr4, float v) {
  return __int_as_float(__builtin_amdgcn_ds_bpermute(addr4, __float_as_int(v)));
}

// variable-index read of .x from a register array via cndmask chain
template<int N>
__device__ __forceinline__ float selNx(const v2f (&a)[N], int idx) {
  float r = a[0].x;
#pragma unroll
  for (int k = 1; k < N; ++k) r = (idx == k) ? a[k].x : r;
  return r;
}

// Parallel cyclic Jacobi, circle-method tournament with fixed physical pairs
// (i, N-1-i). Lane l holds column l of A in av[].x and row l of V in av[].y.
// Row rotation and V rotation share (c,s) -> packed v_pk_fma_f32.
template<int N>
__device__ void jacobi_eig(v2f (&av)[N], int l, int base4, bool laneValid,
                           float tolsq, int maxSweeps)
{
  constexpr int NH = N / 2;
  const int partner = N - 1 - l;
  const int pslot = (l < NH) ? l : partner;
  const int qslot = N - 1 - pslot;
  const int p4 = base4 + 4 * pslot;
  const int q4 = base4 + 4 * qslot;
  const int pr4 = base4 + 4 * partner;
  const int srcl = (l == 0) ? 0 : ((l == 1) ? (N - 1) : (l - 1));
  const int src4 = base4 + 4 * srcl;
  const bool isP = (l < NH);

  float dval = selNx<N>(av, l);   // own diagonal, maintained incrementally
  int sweep = 0;
  while (true) {
    float offAcc = 0.0f;
    for (int r = 0; r < N - 1; ++r) {
      float anti = selNx<N>(av, partner);     // A[partner][l] == apq (sym)
      float app = bperm(p4, dval);
      float aqq = bperm(q4, dval);
      float apq = bperm(p4, anti);

      // rotation via rsq-based rcp/sqrt (NaN-guarded; benign skip for tiny apq)
      bool ok = fabsf(apq) > 1e-18f;
      float apqs = ok ? apq : 1.0f;
      float ir = rsqrtf(apqs * apqs);
      float inva = apqs * ir * ir;                    // 1/apqs (sign-carrying)
      float theta = 0.5f * (aqq - app) * inva;
      float s2t = fminf(theta * theta + 1.0f, 3.0e38f);  // clamp: no inf*0 NaN
      float rs = rsqrtf(s2t);
      float den = fabsf(theta) + s2t * rs;            // |t| + sqrt(t^2+1) >= 1
      float rd = rsqrtf(den * den);
      float tt = den * rd * rd;                       // 1/den
      tt = (theta < 0.0f) ? -tt : tt;
      tt = ok ? tt : 0.0f;
      float c = rsqrtf(tt * tt + 1.0f);
      float s = tt * c;
      offAcc += laneValid ? apq * apq : 0.0f;

      // column update: A <- A*G (my column combines with partner's)
      float seff = isP ? -s : s;
#pragma unroll
      for (int k = 0; k < N; ++k) {
        float pc = bperm(pr4, av[k].x);
        av[k].x = fmaf(c, av[k].x, seff * pc);
      }
      // row update A <- G^T*A fused with V <- V*G (same ci,si: packed fp32)
#pragma unroll
      for (int i = 0; i < NH; ++i) {
        float ci = bperm(base4 + 4 * i, c);
        float si = bperm(base4 + 4 * i, s);
        v2f c2 = {ci, ci}, s2 = {si, si};
        v2f x = av[i], y = av[N - 1 - i];
        v2f m1 = s2 * y;
        v2f m2 = s2 * x;
        av[i]         = __builtin_elementwise_fma(c2, x, -m1);
        av[N - 1 - i] = __builtin_elementwise_fma(c2, y, m2);
      }
      float dnew = isP ? fmaf(-tt, apq, app) : fmaf(tt, apq, aqq);

      // tournament permutation: slot0 pinned, tail rotated; in-place (1 temp).
      // .x moves across lanes (columns travel), .y rotates registers only.
      v2f t0 = av[N - 1];
#pragma unroll
      for (int k = N - 1; k >= 2; --k) {
        av[k].x = bperm(src4, av[k - 1].x);
        av[k].y = av[k - 1].y;
      }
      av[1].x = bperm(src4, t0.x);
      av[1].y = t0.y;
      av[0].x = bperm(src4, av[0].x);
      dval = bperm(src4, dnew);
    }
    ++sweep;
#pragma unroll
    for (int m = 1; m < 64; m <<= 1) offAcc += __shfl_xor(offAcc, m);
    if (sweep >= maxSweeps || offAcc < tolsq) break;   // wave-uniform
  }
}

// block = 256 = 4 waves; each wave owns 3 matrices (20 lanes each; lanes 60..63
// shadow group 2). All LDS after the one barrier is wave-private -> waves run
// decoupled through their Jacobi iterations.
__global__ __launch_bounds__(256, 5)
void spdnet_kernel(const float* __restrict__ X, const float* __restrict__ W1g,
                   const float* __restrict__ W2g, float* __restrict__ out,
                   int nBatch)
{
  __shared__ __align__(16) float sW1[20 * 32];
  __shared__ __align__(16) float sW2[15 * 20];
  __shared__ __align__(16) float sS[4 * 3 * REG];

  const int tid = threadIdx.x;
  const int wave = tid >> 6;
  const int lane = tid & 63;
  const int grp = lane / 20;
  const int l = lane - grp * 20;
  const int g3 = (grp < 3) ? grp : 2;
  const bool activeG = (grp < 3);
  const int wstart = blockIdx.x * 12 + wave * 3;
  const int bm = wstart + g3;
  const bool valid = activeG && (bm < nBatch);
  const int base4 = g3 * 80;
  float* sSw = sS + wave * (3 * REG);
  float* Sm = sSw + g3 * REG;

  for (int i = tid; i < 600; i += 256) sW1[(i / 30) * 32 + (i % 30)] = W1g[i];
  for (int i = tid; i < 300; i += 256) sW2[i] = W2g[i];

  int nm = nBatch - wstart; nm = nm < 0 ? 0 : (nm > 3 ? 3 : nm);
  const float* Xg = X + (size_t)wstart * 900;

  // W1 row l in registers (rows are 8B-aligned)
  float w1r[30];
  {
    const float2* wr = (const float2*)(W1g + l * 30);
#pragma unroll
    for (int k2 = 0; k2 < 15; ++k2) {
      float2 q = wr[k2];
      w1r[2 * k2] = q.x; w1r[2 * k2 + 1] = q.y;
    }
  }

  // t = sym(X) * w1_row(l), accumulated over two 15-row chunks of X:
  //   chunk rows give the X[r,:] part for r in chunk (full k-dot), and the
  //   X[k,:] part contributes X[k][r]*w1[k] to every r.
  float t[30];
#pragma unroll
  for (int r = 0; r < 30; ++r) t[r] = 0.0f;

#pragma unroll
  for (int c = 0; c < 2; ++c) {
    for (int idx = lane; idx < nm * 450; idx += 64) {
      int m = idx / 450;
      int rem = idx - m * 450;
      int rr = rem / 30;
      int kk = rem - rr * 30;
      sSw[m * REG + rr * 32 + kk] = Xg[m * 900 + c * 450 + rem];
    }
    if (c == 0) __syncthreads();         // also covers sW1/sW2
    else __threadfence_block();          // wave-private staging visible

    // (i) rows in chunk: full 30-wide dot
#pragma unroll
    for (int rr = 0; rr < 15; ++rr) {
      const float* row = Sm + rr * 32;
      const float4* row4 = (const float4*)row;
      float acc = 0.0f;
#pragma unroll
      for (int k4 = 0; k4 < 7; ++k4) {
        float4 q = row4[k4];
        acc += q.x * w1r[4 * k4] + q.y * w1r[4 * k4 + 1] +
               q.z * w1r[4 * k4 + 2] + q.w * w1r[4 * k4 + 3];
      }
      acc += row[28] * w1r[28] + row[29] * w1r[29];
      t[c * 15 + rr] += acc;
    }
    // (ii) cols: t[r] += X[k][r]*w1[k] for k in chunk
#pragma unroll
    for (int kk = 0; kk < 15; ++kk) {
      float wk = w1r[c * 15 + kk];
      const float* row = Sm + kk * 32;
      const float4* row4 = (const float4*)row;
#pragma unroll
      for (int r4 = 0; r4 < 7; ++r4) {
        float4 q = row4[r4];
        t[4 * r4 + 0] += q.x * wk; t[4 * r4 + 1] += q.y * wk;
        t[4 * r4 + 2] += q.z * wk; t[4 * r4 + 3] += q.w * wk;
      }
      t[28] += row[28] * wk; t[29] += row[29] * wk;
    }
    if (c == 0) __threadfence_block();   // chunk0 reads done before overwrite
  }
#pragma unroll
  for (int r = 0; r < 30; ++r) t[r] *= 0.5f;

  // a = column l of Y1 = W1*t (+ eps I); V = I (rows, in .y)
  v2f av[20];
#pragma unroll
  for (int i = 0; i < 20; ++i) {
    const float* wrow = sW1 + i * 32;
    const float4* w4 = (const float4*)wrow;
    float acc = 0.0f;
#pragma unroll
    for (int k4 = 0; k4 < 7; ++k4) {
      float4 q = w4[k4];
      acc += q.x * t[4 * k4] + q.y * t[4 * k4 + 1] +
             q.z * t[4 * k4 + 2] + q.w * t[4 * k4 + 3];
    }
    acc += wrow[28] * t[28] + wrow[29] * t[29];
    av[i].x = acc + ((i == l) ? EPSV : 0.0f);
    av[i].y = (i == l) ? 1.0f : 0.0f;
  }

  jacobi_eig<20>(av, l, base4, valid, 2.0e-9f, 12);

  float lam1 = selNx<20>(av, l);
  float gs = sqrtf(fmaxf(lam1, EPSV));

  // write V rows (stride 21); each lane then reads eigenvector column l
  float* Vl = Sm;
  __threadfence_block();
  if (activeG) {
#pragma unroll
    for (int k = 0; k < 20; ++k) Vl[l * 21 + k] = av[k].y;
  }
  __threadfence_block();
  float vcol[20];
#pragma unroll
  for (int r = 0; r < 20; ++r) vcol[r] = Vl[r * 21 + l];

  // u_l = sqrt(max(lam,eps)) * W2 * v_l  ->  Ut[i][l] (overlay at Sm+0)
  float b[15];
#pragma unroll
  for (int i = 0; i < 15; ++i) {
    const float4* w2r = (const float4*)(sW2 + i * 20);
    float acc = 0.0f;
#pragma unroll
    for (int r4 = 0; r4 < 5; ++r4) {
      float4 q = w2r[r4];
      acc += q.x * vcol[4 * r4] + q.y * vcol[4 * r4 + 1] +
             q.z * vcol[4 * r4 + 2] + q.w * vcol[4 * r4 + 3];
    }
    b[i] = acc;
  }
  __threadfence_block();
  if (activeG) {
#pragma unroll
    for (int i = 0; i < 15; ++i) Sm[i * 20 + l] = gs * b[i];
  }
  __threadfence_block();

  // Y2 padded to 16x16 (dummy row/col 15 = 0): a2[r] = <Ut[r][:], Ut[l2][:]>
  const int l2 = l & 15;
  float myrow[20];
  {
    const float4* mr = (const float4*)(Sm + ((l2 < 15) ? l2 : 0) * 20);
    float msk = (l2 < 15) ? 1.0f : 0.0f;
#pragma unroll
    for (int r4 = 0; r4 < 5; ++r4) {
      float4 q = mr[r4];
      myrow[4 * r4]     = q.x * msk; myrow[4 * r4 + 1] = q.y * msk;
      myrow[4 * r4 + 2] = q.z * msk; myrow[4 * r4 + 3] = q.w * msk;
    }
  }
  v2f av2[16];
#pragma unroll
  for (int r = 0; r < 15; ++r) {
    const float4* ur = (const float4*)(Sm + r * 20);
    float acc = 0.0f;
#pragma unroll
    for (int r4 = 0; r4 < 5; ++r4) {
      float4 q = ur[r4];
      acc += q.x * myrow[4 * r4] + q.y * myrow[4 * r4 + 1] +
             q.z * myrow[4 * r4 + 2] + q.w * myrow[4 * r4 + 3];
    }
    av2[r].x = acc + ((r == l2) ? EPSV : 0.0f);
    av2[r].y = (r == l2) ? 1.0f : 0.0f;
  }
  av2[15].x = 0.0f;
  av2[15].y = (l2 == 15) ? 1.0f : 0.0f;

  jacobi_eig<16>(av2, l2, base4, valid && (l < 16), 3.0e-10f, 12);

  float lam2 = selNx<16>(av2, l2);
  float h = logf(fmaxf(lam2, EPSV));   // fused reeig+logeig

  // Wl rows (16x20 at Sm+0), h at Sm+320, triBuf at Sm+336
  __threadfence_block();
  if (activeG && l < 16) {
#pragma unroll
    for (int k = 0; k < 16; ++k) Sm[l2 * 20 + k] = av2[k].y;
    Sm[320 + l2] = h;
  }
  __threadfence_block();

  // M[i][j] = sum_k h_k V2[i][k] V2[j][k]; lane j=l stores triu rows to LDS
  if (activeG && l < 15) {
    float hw[15];
#pragma unroll
    for (int k = 0; k < 15; ++k) hw[k] = Sm[320 + k] * Sm[l * 20 + k];
#pragma unroll
    for (int i = 0; i < 15; ++i) {
      const float* wr = Sm + i * 20;
      float acc = 0.0f;
#pragma unroll
      for (int k = 0; k < 15; ++k) acc += hw[k] * wr[k];
      if (i <= l) Sm[336 + 15 * i - (i * (i - 1)) / 2 + (l - i)] = acc;
    }
  }
  __threadfence_block();

  // coalesced output: 120 floats/matrix, contiguous per wave
  float* og = out + (size_t)wstart * 120;
  for (int idx = lane; idx < nm * 120; idx += 64) {
    int m = idx / 120;
    int off = idx - m * 120;
    og[idx] = sSw[m * REG + 336 + off];
  }
}

extern "C" void kernel_launch(void* const* d_in, const int* in_sizes, int n_in,
                              void* d_out, int out_size, void* d_ws, size_t ws_size,
                              hipStream_t stream) {
  const float* X  = (const float*)d_in[0];
  const float* W1 = (const float*)d_in[1];
  const float* W2 = (const float*)d_in[2];
  float* out = (float*)d_out;
  int nBatch = in_sizes[0] / 900;
  int nBlocks = (nBatch + 11) / 12;   // 12 matrices per 256-thread block
  spdnet_kernel<<<nBlocks, 256, 0, stream>>>(X, W1, W2, out, nBatch);
}

// Round 3
// 5115.709 us; speedup vs baseline: 1.1769x; 1.1769x over previous
//
#include <hip/hip_runtime.h>

#define EPSV 1e-4f
#define REG 484   // floats per matrix LDS region

typedef float v2f __attribute__((ext_vector_type(2)));

__device__ __forceinline__ float bperm(int addr4, float v) {
  return __int_as_float(__builtin_amdgcn_ds_bpermute(addr4, __float_as_int(v)));
}

// variable-index read of .x via cndmask chain (stays in VGPRs)
template<int N>
__device__ __forceinline__ float selX(const v2f (&a)[N], int idx) {
  float r = a[0].x;
#pragma unroll
  for (int k = 1; k < N; ++k) r = (idx == k) ? a[k].x : r;
  return r;
}

// Parallel cyclic Jacobi, tournament pairing on slots (i, N-1-i).
// COLUMNS PINNED TO LANES (no cross-lane column permutation!). Lane l holds
// column l of A in av[].x (rows stored in SLOT order, rotating through
// registers each round) and row l of V in av[].y (V columns in slot order,
// same rotation). Pair (c,s) broadcast via per-group LDS table.
// DS ops/round: 2 bperm (dval/anti) + N bperm (partner column gather)
// + 1 ds_write_b64 + NH/2 ds_read_b128  (vs 3N+4 in the R1 scheme).
template<int N>
__device__ float jacobi_eig(v2f (&av)[N], float dval, int l, int base4,
                            float* csg, bool laneValid,
                            float tolsq, int maxSweeps)
{
  constexpr int NH = N / 2;
  constexpr int NC = N - 1;          // tournament cycle length
  int sl = l;                        // my label's current slot
  int rm = 0;                        // round index mod NC
  int sweep = 0;
  while (true) {
    float offAcc = 0.0f;
    for (int r = 0; r < NC; ++r) {
      // partner slot/label: label at slot t (t>=1) is 1+((t-1-rm) mod NC)
      const int ps = NC - sl;
      int tw = ps - 1 - rm; tw += (tw < 0) ? NC : 0;
      const int pl = (ps == 0) ? 0 : (1 + tw);
      const int pa4 = base4 + 4 * pl;
      const bool isP = (sl < NH);

      float anti = selX<N>(av, ps);          // A[pl][l] (row pl at slot ps)
      float od = bperm(pa4, dval);
      float oa = bperm(pa4, anti);
      // batched partner-column gather (independent bperms -> pipelined)
      float pc[N];
#pragma unroll
      for (int k = 0; k < N; ++k) pc[k] = bperm(pa4, av[k].x);

      // both pair lanes see identical (app,aqq,apq) -> identical (c,s)
      float app = isP ? dval : od;
      float aqq = isP ? od : dval;
      float apq = isP ? anti : oa;

      bool okr = fabsf(apq) > 1e-28f;
      float apqs = okr ? apq : 1.0f;
      float theta = 0.5f * (aqq - app) * __builtin_amdgcn_rcpf(apqs);
      float den = fabsf(theta) + sqrtf(fmaf(theta, theta, 1.0f));
      float tt = __builtin_amdgcn_rcpf(den);   // |t| = 1/(|th|+sqrt(th^2+1))
      tt = (theta < 0.0f) ? -tt : tt;
      tt = okr ? tt : 0.0f;
      float c = rsqrtf(fmaf(tt, tt, 1.0f));
      float s = tt * c;
      offAcc += laneValid ? apq * apq : 0.0f;

      // publish my pair's (c,s); P lane's slot == pair index
      if (isP) { csg[2 * sl] = c; csg[2 * sl + 1] = s; }

      // column update A <- A*G with LOCAL (c,s)
      float seff = isP ? -s : s;
#pragma unroll
      for (int k = 0; k < N; ++k) av[k].x = fmaf(c, av[k].x, seff * pc[k]);

      // fetch all pair (c,s): broadcast b128 reads (conflict-free)
      float4 csq[NH / 2];
#pragma unroll
      for (int j = 0; j < NH / 2; ++j) csq[j] = ((const float4*)csg)[j];

      // row update A <- G^T*A fused with V <- V*G on FIXED slot pairs
#pragma unroll
      for (int i = 0; i < NH; ++i) {
        float ci = (i & 1) ? csq[i >> 1].z : csq[i >> 1].x;
        float si = (i & 1) ? csq[i >> 1].w : csq[i >> 1].y;
        v2f c2 = {ci, ci}, s2 = {si, si};
        v2f x = av[i], y = av[N - 1 - i];
        v2f m1 = s2 * y;
        v2f m2 = s2 * x;
        av[i]         = __builtin_elementwise_fma(c2, x, -m1);
        av[N - 1 - i] = __builtin_elementwise_fma(c2, y, m2);
      }
      dval = isP ? fmaf(-tt, apq, app) : fmaf(tt, apq, aqq);

      // slot rotation: slot0 pinned, tail shifts — registers only, no DS
      v2f keep = av[N - 1];
#pragma unroll
      for (int k = N - 1; k >= 2; --k) av[k] = av[k - 1];
      av[1] = keep;

      sl = (sl == 0) ? 0 : ((sl == NC) ? 1 : sl + 1);
      rm = (rm == NC - 1) ? 0 : rm + 1;
    }
    ++sweep;
#pragma unroll
    for (int m = 1; m < 64; m <<= 1) offAcc += __shfl_xor(offAcc, m);
    if (sweep >= maxSweeps || offAcc < tolsq) break;   // sweep boundary:
  }                                                     // slots == labels
  return dval;   // eigenvalue for label l; eigvec row l of V in av[].y
}

// block = 256 = 4 waves; each wave owns 3 matrices (20 lanes each; lanes
// 60..63 shadow group 2 harmlessly). After the single __syncthreads all LDS
// traffic is wave-private.
__global__ __launch_bounds__(256, 4)
void spdnet_kernel(const float* __restrict__ X, const float* __restrict__ W1g,
                   const float* __restrict__ W2g, float* __restrict__ out,
                   int nBatch)
{
  __shared__ __align__(16) float sW1[20 * 32];
  __shared__ __align__(16) float sW2[15 * 20];
  __shared__ __align__(16) float sS[4 * 3 * REG];
  __shared__ __align__(16) float sCS[4 * 3 * 20];   // per-(wave,group) cs table

  const int tid = threadIdx.x;
  const int wave = tid >> 6;
  const int lane = tid & 63;
  const int grp = lane / 20;
  const int l = lane - grp * 20;
  const int g3 = (grp < 3) ? grp : 2;
  const bool activeG = (grp < 3);
  const int wstart = blockIdx.x * 12 + wave * 3;
  const int bm = wstart + g3;
  const bool valid = activeG && (bm < nBatch);
  const int base4 = g3 * 80;
  float* sSw = sS + wave * (3 * REG);
  float* Sm = sSw + g3 * REG;
  float* csg = sCS + (wave * 3 + g3) * 20;

  for (int i = tid; i < 600; i += 256) sW1[(i / 30) * 32 + (i % 30)] = W1g[i];
  for (int i = tid; i < 300; i += 256) sW2[i] = W2g[i];

  int nm = nBatch - wstart; nm = nm < 0 ? 0 : (nm > 3 ? 3 : nm);
  const float* Xg = X + (size_t)wstart * 900;

  // W1 row l in registers (rows 8B-aligned)
  float w1r[30];
  {
    const float2* wr = (const float2*)(W1g + l * 30);
#pragma unroll
    for (int k2 = 0; k2 < 15; ++k2) {
      float2 q = wr[k2];
      w1r[2 * k2] = q.x; w1r[2 * k2 + 1] = q.y;
    }
  }

  // t = sym(X)*w1_row(l) over two 15-row chunks of X (LDS = 15x32/matrix)
  float t[30];
#pragma unroll
  for (int r = 0; r < 30; ++r) t[r] = 0.0f;

#pragma unroll
  for (int c = 0; c < 2; ++c) {
    for (int idx = lane; idx < nm * 450; idx += 64) {
      int m = idx / 450;
      int rem = idx - m * 450;
      int rr = rem / 30;
      int kk = rem - rr * 30;
      sSw[m * REG + rr * 32 + kk] = Xg[m * 900 + c * 450 + rem];
    }
    if (c == 0) __syncthreads();         // also covers sW1/sW2
    else __threadfence_block();

    // (i) rows in chunk: full 30-wide dot (broadcast LDS reads)
#pragma unroll
    for (int rr = 0; rr < 15; ++rr) {
      const float* row = Sm + rr * 32;
      const float4* row4 = (const float4*)row;
      float acc = 0.0f;
#pragma unroll
      for (int k4 = 0; k4 < 7; ++k4) {
        float4 q = row4[k4];
        acc += q.x * w1r[4 * k4] + q.y * w1r[4 * k4 + 1] +
               q.z * w1r[4 * k4 + 2] + q.w * w1r[4 * k4 + 3];
      }
      acc += row[28] * w1r[28] + row[29] * w1r[29];
      t[c * 15 + rr] += acc;
    }
    // (ii) cols: t[r] += X[k][r]*w1[k] for k in chunk
#pragma unroll
    for (int kk = 0; kk < 15; ++kk) {
      float wk = w1r[c * 15 + kk];
      const float* row = Sm + kk * 32;
      const float4* row4 = (const float4*)row;
#pragma unroll
      for (int r4 = 0; r4 < 7; ++r4) {
        float4 q = row4[r4];
        t[4 * r4 + 0] += q.x * wk; t[4 * r4 + 1] += q.y * wk;
        t[4 * r4 + 2] += q.z * wk; t[4 * r4 + 3] += q.w * wk;
      }
      t[28] += row[28] * wk; t[29] += row[29] * wk;
    }
    if (c == 0) __threadfence_block();
  }
#pragma unroll
  for (int r = 0; r < 30; ++r) t[r] *= 0.5f;

  // a = column l of Y1 = W1*t (+ eps I); V = I
  v2f av[20];
  float dv1 = 0.0f;
#pragma unroll
  for (int i = 0; i < 20; ++i) {
    const float* wrow = sW1 + i * 32;
    const float4* w4 = (const float4*)wrow;
    float acc = 0.0f;
#pragma unroll
    for (int k4 = 0; k4 < 7; ++k4) {
      float4 q = w4[k4];
      acc += q.x * t[4 * k4] + q.y * t[4 * k4 + 1] +
             q.z * t[4 * k4 + 2] + q.w * t[4 * k4 + 3];
    }
    acc += wrow[28] * t[28] + wrow[29] * t[29];
    float val = acc + ((i == l) ? EPSV : 0.0f);
    av[i].x = val;
    av[i].y = (i == l) ? 1.0f : 0.0f;
    dv1 = (i == l) ? val : dv1;
  }

  float lam1 = jacobi_eig<20>(av, dv1, l, base4, csg, valid, 2.0e-9f, 12);
  float gs = sqrtf(fmaxf(lam1, EPSV));

  // write V rows (stride 21); each lane reads eigenvector column l
  float* Vl = Sm;
  __threadfence_block();
  if (activeG) {
#pragma unroll
    for (int k = 0; k < 20; ++k) Vl[l * 21 + k] = av[k].y;
  }
  __threadfence_block();
  float vcol[20];
#pragma unroll
  for (int r = 0; r < 20; ++r) vcol[r] = Vl[r * 21 + l];

  // u_l = sqrt(max(lam,eps)) * W2 * v_l  ->  Ut[i][l] (overlay at Sm+0)
  float b[15];
#pragma unroll
  for (int i = 0; i < 15; ++i) {
    const float4* w2r = (const float4*)(sW2 + i * 20);
    float acc = 0.0f;
#pragma unroll
    for (int r4 = 0; r4 < 5; ++r4) {
      float4 q = w2r[r4];
      acc += q.x * vcol[4 * r4] + q.y * vcol[4 * r4 + 1] +
             q.z * vcol[4 * r4 + 2] + q.w * vcol[4 * r4 + 3];
    }
    b[i] = acc;
  }
  __threadfence_block();
  if (activeG) {
#pragma unroll
    for (int i = 0; i < 15; ++i) Sm[i * 20 + l] = gs * b[i];
  }
  __threadfence_block();

  // Y2 padded to 16x16 (dummy row/col 15 = 0): a2[r] = <Ut[r][:], Ut[l2][:]>
  const int l2 = l & 15;
  float myrow[20];
  {
    const float4* mr = (const float4*)(Sm + ((l2 < 15) ? l2 : 0) * 20);
    float msk = (l2 < 15) ? 1.0f : 0.0f;
#pragma unroll
    for (int r4 = 0; r4 < 5; ++r4) {
      float4 q = mr[r4];
      myrow[4 * r4]     = q.x * msk; myrow[4 * r4 + 1] = q.y * msk;
      myrow[4 * r4 + 2] = q.z * msk; myrow[4 * r4 + 3] = q.w * msk;
    }
  }
  v2f av2[16];
  float dv2 = 0.0f;
#pragma unroll
  for (int r = 0; r < 15; ++r) {
    const float4* ur = (const float4*)(Sm + r * 20);
    float acc = 0.0f;
#pragma unroll
    for (int r4 = 0; r4 < 5; ++r4) {
      float4 q = ur[r4];
      acc += q.x * myrow[4 * r4] + q.y * myrow[4 * r4 + 1] +
             q.z * myrow[4 * r4 + 2] + q.w * myrow[4 * r4 + 3];
    }
    float val = acc + ((r == l2) ? EPSV : 0.0f);
    av2[r].x = val;
    av2[r].y = (r == l2) ? 1.0f : 0.0f;
    dv2 = (r == l2) ? val : dv2;
  }
  av2[15].x = 0.0f;
  av2[15].y = (l2 == 15) ? 1.0f : 0.0f;

  float lam2 = jacobi_eig<16>(av2, dv2, l2, base4, csg,
                              valid && (l < 16), 3.0e-10f, 12);
  float h = logf(fmaxf(lam2, EPSV));   // fused reeig+logeig

  // Wl rows (16x20 at Sm+0), h at Sm+320, triBuf at Sm+336
  __threadfence_block();
  if (activeG && l < 16) {
#pragma unroll
    for (int k = 0; k < 16; ++k) Sm[l2 * 20 + k] = av2[k].y;
    Sm[320 + l2] = h;
  }
  __threadfence_block();

  // M[i][j] = sum_k h_k V2[i][k] V2[j][k]; lane j=l stores triu rows to LDS
  if (activeG && l < 15) {
    float hw[15];
#pragma unroll
    for (int k = 0; k < 15; ++k) hw[k] = Sm[320 + k] * Sm[l * 20 + k];
#pragma unroll
    for (int i = 0; i < 15; ++i) {
      const float* wr = Sm + i * 20;
      float acc = 0.0f;
#pragma unroll
      for (int k = 0; k < 15; ++k) acc += hw[k] * wr[k];
      if (i <= l) Sm[336 + 15 * i - (i * (i - 1)) / 2 + (l - i)] = acc;
    }
  }
  __threadfence_block();

  // coalesced output: 120 floats/matrix, contiguous per wave
  float* og = out + (size_t)wstart * 120;
  for (int idx = lane; idx < nm * 120; idx += 64) {
    int m = idx / 120;
    int off = idx - m * 120;
    og[idx] = sSw[m * REG + 336 + off];
  }
}

extern "C" void kernel_launch(void* const* d_in, const int* in_sizes, int n_in,
                              void* d_out, int out_size, void* d_ws, size_t ws_size,
                              hipStream_t stream) {
  const float* X  = (const float*)d_in[0];
  const float* W1 = (const float*)d_in[1];
  const float* W2 = (const float*)d_in[2];
  float* out = (float*)d_out;
  int nBatch = in_sizes[0] / 900;
  int nBlocks = (nBatch + 11) / 12;   // 12 matrices per 256-thread block
  spdnet_kernel<<<nBlocks, 256, 0, stream>>>(X, W1, W2, out, nBatch);
}